// Round 13
// baseline (69.445 us; speedup 1.0000x reference)
//
#include <hip/hip_runtime.h>
#include <math.h>

#define NV 24
#define NB 8
#define NS 512
#define NTOK 4096       // NB*NS
#define H1 128
#define H2 64
#define SH1 256
#define SH2 128
#define IH 32
#define NP 576          // NV*NV

typedef short bf16x8 __attribute__((ext_vector_type(8)));
typedef float f32x4 __attribute__((ext_vector_type(4)));

__device__ __forceinline__ short f2bf(float f) {
    union { float f; unsigned u; } x; x.f = f;
    unsigned r = x.u + 0x7fffu + ((x.u >> 16) & 1u);   // RNE
    return (short)(r >> 16);
}

__device__ __forceinline__ float blk_reduce(float x, float* red, int t) {
#pragma unroll
    for (int o = 32; o > 0; o >>= 1) x += __shfl_xor(x, o);
    if ((t & 63) == 0) red[t >> 6] = x;
    __syncthreads();
    float r = red[0] + red[1] + red[2] + red[3];
    __syncthreads();
    return r;
}

// ---------------- ws layout (floats) ----------------
// [0, 576)            cov
// [1024, 99328)       dataT [NV][NTOK]
// [99328, 246784)     sW1T  [256][576]
// [246784, 279552)    sW2T  [128][256]
// [279552, 353280)    sW3T  [576][128]

// K1: blocks 0..383 transpose data; blocks 384..445 repack weights (64x64
// LDS tile transpose -> contiguous GEMV rows for k_adj).
__global__ __launch_bounds__(256) void k_prep(
    const float* __restrict__ data, float* __restrict__ dataT,
    const float* __restrict__ sW1, const float* __restrict__ sW2,
    const float* __restrict__ sW3,
    float* __restrict__ sW1T, float* __restrict__ sW2T,
    float* __restrict__ sW3T) {
    const int bx = blockIdx.x, t = threadIdx.x;
    if (bx < 384) {
        int idx = bx * 256 + t;
        int n = idx / NV, v = idx % NV;
        dataT[v * NTOK + n] = data[idx];
        return;
    }
    __shared__ float T[64][65];
    int rb = bx - 384;
    const float* src; float* dst; int R, C, ti, tj;
    if (rb < 36)      { src = sW1; dst = sW1T; R = 576; C = 256; ti = rb >> 2;       tj = rb & 3; }
    else if (rb < 44) { src = sW2; dst = sW2T; R = 256; C = 128; ti = (rb - 36) >> 1; tj = (rb - 36) & 1; }
    else              { src = sW3; dst = sW3T; R = 128; C = 576; ti = (rb - 44) / 9;  tj = (rb - 44) % 9; }
    const int col = t & 63, rq = t >> 6;
#pragma unroll
    for (int i = 0; i < 16; ++i) {
        int row = i * 4 + rq;
        T[row][col] = src[(ti * 64 + row) * C + tj * 64 + col];
    }
    __syncthreads();
#pragma unroll
    for (int i = 0; i < 16; ++i) {
        int row = i * 4 + rq;
        dst[(tj * 64 + row) * R + ti * 64 + col] = T[col][row];
    }
}

// K2: covavg (576 blocks)
__global__ __launch_bounds__(256) void k_cov(const float* __restrict__ dataT,
                                             float* __restrict__ cov) {
    __shared__ float red[256];
    const int bx = blockIdx.x;
    const int t = threadIdx.x;
    int i = bx / NV, j = bx % NV;
    const float* ri = dataT + i * NTOK;
    const float* rj = dataT + j * NTOK;
    float ai0 = 0.f, ai1 = 0.f, aj0 = 0.f, aj1 = 0.f;
#pragma unroll
    for (int b = 0; b < NB; ++b) {
        ai0 += ri[b * NS + t];       ai1 += ri[b * NS + t + 256];
        aj0 += rj[b * NS + t];       aj1 += rj[b * NS + t + 256];
    }
    ai0 *= 0.125f; ai1 *= 0.125f; aj0 *= 0.125f; aj1 *= 0.125f;
    float si = blk_reduce(ai0 + ai1, red, t);
    float sj = blk_reduce(aj0 + aj1, red, t);
    float mi = si * (1.f / NS), mj = sj * (1.f / NS);
    float sd = (ai0 - mi) * (aj0 - mj) + (ai1 - mi) * (aj1 - mj);
    sd = blk_reduce(sd, red, t);
    if (t == 0) cov[bx] = sd;
}

// K3: structure MLP, 72 blocks x 512 threads, TRANSPOSED weights so every
// thread's loads are contiguous (one base reg + imm offsets -> all loads
// independent; no address-VGPR strip-mining). Accumulation order == R12.
__global__ __launch_bounds__(512) void k_adj(
    const float* __restrict__ cov,
    const float* __restrict__ sW1T, const float* __restrict__ sb1,
    const float* __restrict__ sW2T, const float* __restrict__ sb2,
    const float* __restrict__ sW3T, const float* __restrict__ sb3,
    float* __restrict__ out_adj) {
    __shared__ float corrL[NP];
    __shared__ float stdL[NV];
    __shared__ float h1L[SH1];
    __shared__ float h2L[SH2];
    __shared__ float P[512];
    const int b = blockIdx.x;          // outputs [b*8, b*8+8)
    const int t = threadIdx.x;
    if (t < NV) stdL[t] = sqrtf(cov[t * (NV + 1)]);
    __syncthreads();
    for (int o = t; o < NP; o += 512) {
        int i = o / NV, j = o % NV;
        float q = fabsf(cov[o] / (stdL[i] * stdL[j]));
        if (isnan(q)) q = 0.f;
        if (i == j) q = 0.f;
        corrL[o] = q;
    }
    __syncthreads();
    // layer1: thread (o = t&255, kh = t>>8): contiguous 288-float run
    {
        const int o = t & 255, kh = t >> 8;
        const float4* base = (const float4*)(sW1T + o * 576 + kh * 288);
        const float* cb = corrL + kh * 288;
        float a = 0.f;
#pragma unroll
        for (int kb = 0; kb < 6; ++kb) {
            float4 w[12];
#pragma unroll
            for (int u = 0; u < 12; ++u) w[u] = base[kb * 12 + u];
#pragma unroll
            for (int u = 0; u < 12; ++u) {
                int k0 = kb * 48 + u * 4;
                a = fmaf(cb[k0 + 0], w[u].x, a);
                a = fmaf(cb[k0 + 1], w[u].y, a);
                a = fmaf(cb[k0 + 2], w[u].z, a);
                a = fmaf(cb[k0 + 3], w[u].w, a);
            }
        }
        P[t] = a;
    }
    __syncthreads();
    if (t < SH1) h1L[t] = fmaxf(P[t] + P[256 + t] + sb1[t], 0.f);
    __syncthreads();
    // layer2: thread (o = t&127, kq = t>>7): contiguous 64-float run, 1 batch
    {
        const int o = t & 127, kq = t >> 7;
        const float4* base = (const float4*)(sW2T + o * 256 + kq * 64);
        float4 w[16];
#pragma unroll
        for (int u = 0; u < 16; ++u) w[u] = base[u];
        float a = 0.f;
#pragma unroll
        for (int u = 0; u < 16; ++u) {
            int k0 = kq * 64 + u * 4;
            a = fmaf(h1L[k0 + 0], w[u].x, a);
            a = fmaf(h1L[k0 + 1], w[u].y, a);
            a = fmaf(h1L[k0 + 2], w[u].z, a);
            a = fmaf(h1L[k0 + 3], w[u].w, a);
        }
        P[t] = a;
    }
    __syncthreads();
    if (t < SH2)
        h2L[t] = fmaxf(P[t] + P[128 + t] + P[256 + t] + P[384 + t] + sb2[t], 0.f);
    __syncthreads();
    // layer3: thread (oq = t&7, kq = t>>3): contiguous float2, 1 batch
    {
        const int oq = t & 7, kq = t >> 3;
        const float2 w = *(const float2*)(sW3T + (b * 8 + oq) * 128 + kq * 2);
        P[t] = fmaf(h2L[kq * 2], w.x, h2L[kq * 2 + 1] * w.y);
    }
    __syncthreads();
    if (t < 8) {
        int oo = b * 8 + t;
        float s = sb3[oo];
#pragma unroll
        for (int kq = 0; kq < 64; ++kq) s += P[kq * 8 + t];
        float sg = 1.f / (1.f + expf(-s));
        int i = oo / NV, j = oo % NV;
        out_adj[oo] = (j > i) ? sg : 0.f;
    }
}

// K4: blocks 0..767 = per-variable MFMA pred MLP (128-token chunks);
// blocks 768..1343 = pairwise ind MLPs.
__global__ __launch_bounds__(256) void k_predind(
    const float* __restrict__ data,
    const float* __restrict__ mW1, const float* __restrict__ mb1,
    const float* __restrict__ mW2, const float* __restrict__ mb2,
    const float* __restrict__ mW3, const float* __restrict__ mb3,
    const float* __restrict__ adj,
    float* __restrict__ out_pred,
    const float* __restrict__ dataT,
    const float* __restrict__ iW1, const float* __restrict__ ib1,
    const float* __restrict__ iW2, const float* __restrict__ ib2,
    float* __restrict__ out_ind) {
    __shared__ short Xl[128 * 40];     // 10 KB
    __shared__ short WH[12288];        // 24 KB
    const int bx = blockIdx.x;
    const int t = threadIdx.x;

    if (bx < 768) {
        // ---------------- pred ----------------
        const int v = bx % NV;
        const int chunk = bx / NV;     // 0..31

        bool hp = false;
#pragma unroll
        for (int r = 0; r < NV; ++r) hp = hp || (adj[r * NV + v] > 0.5f);
        if (!hp) {
            if (t < 128) {
                int tok = chunk * 128 + t;
                out_pred[tok * NV + v] = data[tok * NV + v];
            }
            return;
        }

        short* W1B = WH;                   // 32*128
        short* W2B = WH + 4096;            // 128*64
        short* Hl = WH;                    // aliased: 4 waves * 2048 shorts

        if (t < 128) {
            int tok = chunk * 128 + t;
            const float4* dr4 = (const float4*)(data + tok * NV);
            float d[24];
#pragma unroll
            for (int q = 0; q < 6; ++q) {
                float4 u = dr4[q];
                d[q * 4 + 0] = u.x; d[q * 4 + 1] = u.y; d[q * 4 + 2] = u.z; d[q * 4 + 3] = u.w;
            }
            short xr[32];
#pragma unroll
            for (int j = 0; j < 23; ++j) {
                int src = j + (j >= v ? 1 : 0);
                xr[j] = f2bf(d[src]);
            }
            xr[23] = f2bf(1.0f);
#pragma unroll
            for (int j = 24; j < 32; ++j) xr[j] = 0;
            short* xp = Xl + t * 40;
#pragma unroll
            for (int q = 0; q < 4; ++q)
                *(bf16x8*)(xp + q * 8) = *(bf16x8*)(xr + q * 8);
        }
        // stage W1 (float4, mask+bias folded)
        if (t < 184) {
            int k = t >> 3, h8 = (t & 7) * 16;
            int src = k + (k >= v ? 1 : 0);
            float pm = (adj[src * NV + v] > 0.5f) ? 1.f : 0.f;
            const float4* wr = (const float4*)(mW1 + (v * 23 + k) * 128 + h8);
            float wv[16];
#pragma unroll
            for (int q = 0; q < 4; ++q) {
                float4 u = wr[q];
                wv[q * 4 + 0] = u.x; wv[q * 4 + 1] = u.y;
                wv[q * 4 + 2] = u.z; wv[q * 4 + 3] = u.w;
            }
            int kb = (k >> 3) & 3, e = k & 7;
#pragma unroll
            for (int q = 0; q < 16; ++q) {
                int h = h8 + q;
                int nt = h >> 4, nn = h & 15;
                W1B[((nt * 4 + kb) * 16 + nn) * 8 + e] = f2bf(wv[q] * pm);
            }
        } else if (t < 200) {
            int h8 = (t - 184) * 8;
            const float4* br = (const float4*)(mb1 + v * 128 + h8);
            float bv[8];
#pragma unroll
            for (int q = 0; q < 2; ++q) {
                float4 u = br[q];
                bv[q * 4 + 0] = u.x; bv[q * 4 + 1] = u.y;
                bv[q * 4 + 2] = u.z; bv[q * 4 + 3] = u.w;
            }
#pragma unroll
            for (int q = 0; q < 8; ++q) {
                int h = h8 + q;
                int nt = h >> 4, nn = h & 15;
                W1B[((nt * 4 + 2) * 16 + nn) * 8 + 7] = f2bf(bv[q]);  // k=23
            }
        }
        if (t < 128) {
            int nt = t >> 4, nn = t & 15;
#pragma unroll
            for (int e = 0; e < 8; ++e)
                W1B[((nt * 4 + 3) * 16 + nn) * 8 + e] = 0;
        }
        // stage W2 (float4)
        {
            int k = t >> 1, n0 = (t & 1) * 32;
            const float4* wr = (const float4*)(mW2 + (v * 128 + k) * 64 + n0);
            float wv[32];
#pragma unroll
            for (int q = 0; q < 8; ++q) {
                float4 u = wr[q];
                wv[q * 4 + 0] = u.x; wv[q * 4 + 1] = u.y;
                wv[q * 4 + 2] = u.z; wv[q * 4 + 3] = u.w;
            }
            int s = k >> 5, kb = (k >> 3) & 3, e = k & 7;
#pragma unroll
            for (int q = 0; q < 32; ++q) {
                int n = n0 + q;
                int nt = n >> 4, nn = n & 15;
                W2B[(((s * 4 + nt) * 4 + kb) * 16 + nn) * 8 + e] = f2bf(wv[q]);
            }
        }
        __syncthreads();

        const int lane = t & 63;
        const int wid = t >> 6;
        const int ml = lane & 15;
        const int kb = lane >> 4;
        short* Hw = Hl + wid * 2048;

        bf16x8 w1f[8], w2f[16];
#pragma unroll
        for (int nt = 0; nt < 8; ++nt)
            w1f[nt] = *(bf16x8*)(W1B + (nt * 64 + lane) * 8);
#pragma unroll
        for (int q = 0; q < 16; ++q)
            w2f[q] = *(bf16x8*)(W2B + (q * 64 + lane) * 8);

        float b2r[4], w3r[4];
#pragma unroll
        for (int nt = 0; nt < 4; ++nt) {
            b2r[nt] = mb2[v * 64 + nt * 16 + ml];
            w3r[nt] = mW3[v * 64 + nt * 16 + ml];
        }
        float b3v = mb3[v];

        __syncthreads();   // W1B/W2B fully read before Hl (aliased) written

#pragma unroll
        for (int mt = 0; mt < 2; ++mt) {
            int lt = wid * 32 + mt * 16 + ml;
            bf16x8 a1 = *(bf16x8*)(Xl + lt * 40 + kb * 8);
            f32x4 c1[8] = {};
#pragma unroll
            for (int nt = 0; nt < 8; ++nt)
                c1[nt] = __builtin_amdgcn_mfma_f32_16x16x32_bf16(a1, w1f[nt], c1[nt], 0, 0, 0);
#pragma unroll
            for (int nt = 0; nt < 8; ++nt) {
#pragma unroll
                for (int r = 0; r < 4; ++r) {
                    int m = kb * 4 + r;
                    int h = nt * 16 + ml;
                    int bo = (m * 256 + h * 2) ^ ((m & 7) << 4);
                    *(short*)((char*)Hw + bo) = f2bf(fmaxf(c1[nt][r], 0.f));
                }
            }
            f32x4 c2[4] = {};
#pragma unroll
            for (int s = 0; s < 4; ++s) {
                int c0 = s * 32 + kb * 8;
                int bo = (ml * 256 + c0 * 2) ^ ((ml & 7) << 4);
                bf16x8 a2 = *(bf16x8*)((char*)Hw + bo);
#pragma unroll
                for (int nt = 0; nt < 4; ++nt)
                    c2[nt] = __builtin_amdgcn_mfma_f32_16x16x32_bf16(a2, w2f[s * 4 + nt], c2[nt], 0, 0, 0);
            }
            float sacc[4] = {0.f, 0.f, 0.f, 0.f};
#pragma unroll
            for (int nt = 0; nt < 4; ++nt) {
#pragma unroll
                for (int r = 0; r < 4; ++r)
                    sacc[r] += fmaxf(c2[nt][r] + b2r[nt], 0.f) * w3r[nt];
            }
#pragma unroll
            for (int o = 1; o < 16; o <<= 1) {
#pragma unroll
                for (int r = 0; r < 4; ++r)
                    sacc[r] += __shfl_xor(sacc[r], o);
            }
            if (ml == 0) {
                int tokb = chunk * 128 + wid * 32 + mt * 16 + kb * 4;
#pragma unroll
                for (int r = 0; r < 4; ++r)
                    out_pred[(tokb + r) * NV + v] = sacc[r] + b3v;
            }
        }
    } else {
        // ---------------- ind ----------------
        int p = bx - 768;
        int i = p / NV, j = p % NV;
        float w0[IH], w1[IH], bb[IH], w2[IH];
        const float4* A4 = (const float4*)(iW1 + p * 2 * IH);
        const float4* B4 = (const float4*)(ib1 + p * IH);
        const float4* C4 = (const float4*)(iW2 + p * IH);
#pragma unroll
        for (int q = 0; q < 8; ++q) {
            float4 u = A4[q];
            w0[q * 4 + 0] = u.x; w0[q * 4 + 1] = u.y; w0[q * 4 + 2] = u.z; w0[q * 4 + 3] = u.w;
            float4 v4 = A4[8 + q];
            w1[q * 4 + 0] = v4.x; w1[q * 4 + 1] = v4.y; w1[q * 4 + 2] = v4.z; w1[q * 4 + 3] = v4.w;
            float4 b4 = B4[q];
            bb[q * 4 + 0] = b4.x; bb[q * 4 + 1] = b4.y; bb[q * 4 + 2] = b4.z; bb[q * 4 + 3] = b4.w;
            float4 c4 = C4[q];
            w2[q * 4 + 0] = c4.x; w2[q * 4 + 1] = c4.y; w2[q * 4 + 2] = c4.z; w2[q * 4 + 3] = c4.w;
        }
        float b2v = ib2[p];
        const float* di_p = dataT + i * NTOK;
        const float* dj_p = dataT + j * NTOK;
        float acc = 0.f;
#pragma unroll 2
        for (int k = 0; k < NTOK / 256; ++k) {
            int n = k * 256 + t;
            float di = di_p[n];
            float dj = dj_p[n];
            float s = b2v;
#pragma unroll
            for (int h = 0; h < IH; ++h) {
                float a = fmaf(di, w0[h], fmaf(dj, w1[h], bb[h]));
                a = fmaxf(a, 0.f);
                s = fmaf(a, w2[h], s);
            }
            acc += 1.f / (1.f + expf(-s));
        }
        float* red = (float*)Xl;
        red[t] = acc;
        __syncthreads();
        for (int st = 128; st > 0; st >>= 1) {
            if (t < st) red[t] += red[t + st];
            __syncthreads();
        }
        if (t == 0) out_ind[p] = red[0] * (1.f / NTOK);
    }
}

extern "C" void kernel_launch(void* const* d_in, const int* in_sizes, int n_in,
                              void* d_out, int out_size, void* d_ws, size_t ws_size,
                              hipStream_t stream) {
    const float* data = (const float*)d_in[0];
    const float* sW1 = (const float*)d_in[1];
    const float* sb1 = (const float*)d_in[2];
    const float* sW2 = (const float*)d_in[3];
    const float* sb2 = (const float*)d_in[4];
    const float* sW3 = (const float*)d_in[5];
    const float* sb3 = (const float*)d_in[6];
    const float* mW1 = (const float*)d_in[7];
    const float* mb1 = (const float*)d_in[8];
    const float* mW2 = (const float*)d_in[9];
    const float* mb2 = (const float*)d_in[10];
    const float* mW3 = (const float*)d_in[11];
    const float* mb3 = (const float*)d_in[12];
    const float* iW1 = (const float*)d_in[13];
    const float* ib1 = (const float*)d_in[14];
    const float* iW2 = (const float*)d_in[15];
    const float* ib2 = (const float*)d_in[16];

    float* out = (float*)d_out;
    float* ws = (float*)d_ws;
    float* ws_cov = ws;
    float* ws_dataT = ws + 1024;
    float* ws_sW1T = ws + 99328;
    float* ws_sW2T = ws + 246784;
    float* ws_sW3T = ws + 279552;

    k_prep<<<dim3(446), dim3(256), 0, stream>>>(data, ws_dataT, sW1, sW2, sW3,
                                                ws_sW1T, ws_sW2T, ws_sW3T);
    k_cov<<<dim3(NP), dim3(256), 0, stream>>>(ws_dataT, ws_cov);
    k_adj<<<dim3(72), dim3(512), 0, stream>>>(ws_cov, ws_sW1T, sb1, ws_sW2T, sb2,
                                              ws_sW3T, sb3, out);
    k_predind<<<dim3(768 + NP), dim3(256), 0, stream>>>(
        data, mW1, mb1, mW2, mb2, mW3, mb3, out, out + NP,
        ws_dataT, iW1, ib1, iW2, ib2, out + NP + NTOK * NV);
}

// Round 14
// 51.135 us; speedup vs baseline: 1.3581x; 1.3581x over previous
//
#include <hip/hip_runtime.h>
#include <math.h>

#define NV 24
#define NB 8
#define NS 512
#define NTOK 4096       // NB*NS
#define H1 128
#define H2 64
#define SH1 256
#define SH2 128
#define IH 32
#define NP 576          // NV*NV

typedef short bf16x8 __attribute__((ext_vector_type(8)));
typedef float f32x4 __attribute__((ext_vector_type(4)));

__device__ __forceinline__ short f2bf(float f) {
    union { float f; unsigned u; } x; x.f = f;
    unsigned r = x.u + 0x7fffu + ((x.u >> 16) & 1u);   // RNE
    return (short)(r >> 16);
}

__device__ __forceinline__ float blk_reduce(float x, float* red, int t) {
#pragma unroll
    for (int o = 32; o > 0; o >>= 1) x += __shfl_xor(x, o);
    if ((t & 63) == 0) red[t >> 6] = x;
    __syncthreads();
    float r = red[0] + red[1] + red[2] + red[3];
    __syncthreads();
    return r;
}

// ---------------- ws layout (floats) ----------------
// [0, 576)            cov
// [576, 832)          h1
// [832, 960)          h2
// [1024, 99328)       dataT [NV][NTOK]
// [99328, 246784)     sW1T  [256][576]
// [246784, 279552)    sW2T  [128][256]
// [279552, 353280)    sW3T  [576][128]

// K1: blocks 0..383 transpose data; blocks 384..445 repack weights (64x64
// LDS tile transpose -> per-output contiguous GEMV rows).
__global__ __launch_bounds__(256) void k_prep(
    const float* __restrict__ data, float* __restrict__ dataT,
    const float* __restrict__ sW1, const float* __restrict__ sW2,
    const float* __restrict__ sW3,
    float* __restrict__ sW1T, float* __restrict__ sW2T,
    float* __restrict__ sW3T) {
    const int bx = blockIdx.x, t = threadIdx.x;
    if (bx < 384) {
        int idx = bx * 256 + t;
        int n = idx / NV, v = idx % NV;
        dataT[v * NTOK + n] = data[idx];
        return;
    }
    __shared__ float T[64][65];
    int rb = bx - 384;
    const float* src; float* dst; int R, C, ti, tj;
    if (rb < 36)      { src = sW1; dst = sW1T; R = 576; C = 256; ti = rb >> 2;       tj = rb & 3; }
    else if (rb < 44) { src = sW2; dst = sW2T; R = 256; C = 128; ti = (rb - 36) >> 1; tj = (rb - 36) & 1; }
    else              { src = sW3; dst = sW3T; R = 128; C = 576; ti = (rb - 44) / 9;  tj = (rb - 44) % 9; }
    const int col = t & 63, rq = t >> 6;
#pragma unroll
    for (int i = 0; i < 16; ++i) {
        int row = i * 4 + rq;
        T[row][col] = src[(ti * 64 + row) * C + tj * 64 + col];
    }
    __syncthreads();
#pragma unroll
    for (int i = 0; i < 16; ++i) {
        int row = i * 4 + rq;
        dst[(tj * 64 + row) * R + ti * 64 + col] = T[col][row];
    }
}

// K2: covavg (576 blocks)
__global__ __launch_bounds__(256) void k_cov(const float* __restrict__ dataT,
                                             float* __restrict__ cov) {
    __shared__ float red[256];
    const int bx = blockIdx.x;
    const int t = threadIdx.x;
    int i = bx / NV, j = bx % NV;
    const float* ri = dataT + i * NTOK;
    const float* rj = dataT + j * NTOK;
    float ai0 = 0.f, ai1 = 0.f, aj0 = 0.f, aj1 = 0.f;
#pragma unroll
    for (int b = 0; b < NB; ++b) {
        ai0 += ri[b * NS + t];       ai1 += ri[b * NS + t + 256];
        aj0 += rj[b * NS + t];       aj1 += rj[b * NS + t + 256];
    }
    ai0 *= 0.125f; ai1 *= 0.125f; aj0 *= 0.125f; aj1 *= 0.125f;
    float si = blk_reduce(ai0 + ai1, red, t);
    float sj = blk_reduce(aj0 + aj1, red, t);
    float mi = si * (1.f / NS), mj = sj * (1.f / NS);
    float sd = (ai0 - mi) * (aj0 - mj) + (ai1 - mi) * (aj1 - mj);
    sd = blk_reduce(sd, red, t);
    if (t == 0) cov[bx] = sd;
}

// K3: layer1 -- ONE BLOCK PER OUTPUT (256 blocks). Lane-coalesced contiguous
// row read (2.25 KB/block), one latency batch, zero redundancy.
__global__ __launch_bounds__(256) void k_adj1(
    const float* __restrict__ cov,
    const float* __restrict__ sW1T, const float* __restrict__ sb1,
    float* __restrict__ h1out) {
    __shared__ float corrL[NP];
    __shared__ float stdL[NV];
    __shared__ float red[256];
    const int o = blockIdx.x, t = threadIdx.x;
    if (t < NV) stdL[t] = sqrtf(cov[t * (NV + 1)]);
    __syncthreads();
    for (int k = t; k < NP; k += 256) {
        int i = k / NV, j = k % NV;
        float q = fabsf(cov[k] / (stdL[i] * stdL[j]));
        if (isnan(q)) q = 0.f;
        if (i == j) q = 0.f;
        corrL[k] = q;
    }
    __syncthreads();
    const float* w = sW1T + o * 576;
    float w0 = w[t], w1 = w[256 + t];
    float w2 = (t < 64) ? w[512 + t] : 0.f;
    float c2 = (t < 64) ? corrL[512 + t] : 0.f;
    float a = corrL[t] * w0 + corrL[256 + t] * w1 + c2 * w2;
    a = blk_reduce(a, red, t);
    if (t == 0) h1out[o] = fmaxf(a + sb1[o], 0.f);
}

// K4: layer2 -- 128 blocks x 256 threads, one k per thread.
__global__ __launch_bounds__(256) void k_adj2(
    const float* __restrict__ h1,
    const float* __restrict__ sW2T, const float* __restrict__ sb2,
    float* __restrict__ h2out) {
    __shared__ float red[256];
    const int o = blockIdx.x, t = threadIdx.x;
    float a = h1[t] * sW2T[o * 256 + t];
    a = blk_reduce(a, red, t);
    if (t == 0) h2out[o] = fmaxf(a + sb2[o], 0.f);
}

// K5: layer3 -- 576 blocks, 128 active lanes, sigmoid + triu.
__global__ __launch_bounds__(256) void k_adj3(
    const float* __restrict__ h2,
    const float* __restrict__ sW3T, const float* __restrict__ sb3,
    float* __restrict__ out_adj) {
    __shared__ float red[256];
    const int oo = blockIdx.x, t = threadIdx.x;
    float a = (t < SH2) ? h2[t] * sW3T[oo * 128 + t] : 0.f;
    a = blk_reduce(a, red, t);
    if (t == 0) {
        float sg = 1.f / (1.f + expf(-(a + sb3[oo])));
        int i = oo / NV, j = oo % NV;
        out_adj[oo] = (j > i) ? sg : 0.f;
    }
}

// K6: blocks 0..767 = per-variable MFMA pred MLP (128-token chunks);
// blocks 768..1343 = pairwise ind MLPs.
__global__ __launch_bounds__(256) void k_predind(
    const float* __restrict__ data,
    const float* __restrict__ mW1, const float* __restrict__ mb1,
    const float* __restrict__ mW2, const float* __restrict__ mb2,
    const float* __restrict__ mW3, const float* __restrict__ mb3,
    const float* __restrict__ adj,
    float* __restrict__ out_pred,
    const float* __restrict__ dataT,
    const float* __restrict__ iW1, const float* __restrict__ ib1,
    const float* __restrict__ iW2, const float* __restrict__ ib2,
    float* __restrict__ out_ind) {
    __shared__ short Xl[128 * 40];     // 10 KB
    __shared__ short WH[12288];        // 24 KB
    const int bx = blockIdx.x;
    const int t = threadIdx.x;

    if (bx < 768) {
        // ---------------- pred ----------------
        const int v = bx % NV;
        const int chunk = bx / NV;     // 0..31

        bool hp = false;
#pragma unroll
        for (int r = 0; r < NV; ++r) hp = hp || (adj[r * NV + v] > 0.5f);
        if (!hp) {
            if (t < 128) {
                int tok = chunk * 128 + t;
                out_pred[tok * NV + v] = data[tok * NV + v];
            }
            return;
        }

        short* W1B = WH;                   // 32*128
        short* W2B = WH + 4096;            // 128*64
        short* Hl = WH;                    // aliased: 4 waves * 2048 shorts

        if (t < 128) {
            int tok = chunk * 128 + t;
            const float4* dr4 = (const float4*)(data + tok * NV);
            float d[24];
#pragma unroll
            for (int q = 0; q < 6; ++q) {
                float4 u = dr4[q];
                d[q * 4 + 0] = u.x; d[q * 4 + 1] = u.y; d[q * 4 + 2] = u.z; d[q * 4 + 3] = u.w;
            }
            short xr[32];
#pragma unroll
            for (int j = 0; j < 23; ++j) {
                int src = j + (j >= v ? 1 : 0);
                xr[j] = f2bf(d[src]);
            }
            xr[23] = f2bf(1.0f);
#pragma unroll
            for (int j = 24; j < 32; ++j) xr[j] = 0;
            short* xp = Xl + t * 40;
#pragma unroll
            for (int q = 0; q < 4; ++q)
                *(bf16x8*)(xp + q * 8) = *(bf16x8*)(xr + q * 8);
        }
        // stage W1 (float4, mask+bias folded)
        if (t < 184) {
            int k = t >> 3, h8 = (t & 7) * 16;
            int src = k + (k >= v ? 1 : 0);
            float pm = (adj[src * NV + v] > 0.5f) ? 1.f : 0.f;
            const float4* wr = (const float4*)(mW1 + (v * 23 + k) * 128 + h8);
            float wv[16];
#pragma unroll
            for (int q = 0; q < 4; ++q) {
                float4 u = wr[q];
                wv[q * 4 + 0] = u.x; wv[q * 4 + 1] = u.y;
                wv[q * 4 + 2] = u.z; wv[q * 4 + 3] = u.w;
            }
            int kb = (k >> 3) & 3, e = k & 7;
#pragma unroll
            for (int q = 0; q < 16; ++q) {
                int h = h8 + q;
                int nt = h >> 4, nn = h & 15;
                W1B[((nt * 4 + kb) * 16 + nn) * 8 + e] = f2bf(wv[q] * pm);
            }
        } else if (t < 200) {
            int h8 = (t - 184) * 8;
            const float4* br = (const float4*)(mb1 + v * 128 + h8);
            float bv[8];
#pragma unroll
            for (int q = 0; q < 2; ++q) {
                float4 u = br[q];
                bv[q * 4 + 0] = u.x; bv[q * 4 + 1] = u.y;
                bv[q * 4 + 2] = u.z; bv[q * 4 + 3] = u.w;
            }
#pragma unroll
            for (int q = 0; q < 8; ++q) {
                int h = h8 + q;
                int nt = h >> 4, nn = h & 15;
                W1B[((nt * 4 + 2) * 16 + nn) * 8 + 7] = f2bf(bv[q]);  // k=23
            }
        }
        if (t < 128) {
            int nt = t >> 4, nn = t & 15;
#pragma unroll
            for (int e = 0; e < 8; ++e)
                W1B[((nt * 4 + 3) * 16 + nn) * 8 + e] = 0;
        }
        // stage W2 (float4)
        {
            int k = t >> 1, n0 = (t & 1) * 32;
            const float4* wr = (const float4*)(mW2 + (v * 128 + k) * 64 + n0);
            float wv[32];
#pragma unroll
            for (int q = 0; q < 8; ++q) {
                float4 u = wr[q];
                wv[q * 4 + 0] = u.x; wv[q * 4 + 1] = u.y;
                wv[q * 4 + 2] = u.z; wv[q * 4 + 3] = u.w;
            }
            int s = k >> 5, kb = (k >> 3) & 3, e = k & 7;
#pragma unroll
            for (int q = 0; q < 32; ++q) {
                int n = n0 + q;
                int nt = n >> 4, nn = n & 15;
                W2B[(((s * 4 + nt) * 4 + kb) * 16 + nn) * 8 + e] = f2bf(wv[q]);
            }
        }
        __syncthreads();

        const int lane = t & 63;
        const int wid = t >> 6;
        const int ml = lane & 15;
        const int kb = lane >> 4;
        short* Hw = Hl + wid * 2048;

        bf16x8 w1f[8], w2f[16];
#pragma unroll
        for (int nt = 0; nt < 8; ++nt)
            w1f[nt] = *(bf16x8*)(W1B + (nt * 64 + lane) * 8);
#pragma unroll
        for (int q = 0; q < 16; ++q)
            w2f[q] = *(bf16x8*)(W2B + (q * 64 + lane) * 8);

        float b2r[4], w3r[4];
#pragma unroll
        for (int nt = 0; nt < 4; ++nt) {
            b2r[nt] = mb2[v * 64 + nt * 16 + ml];
            w3r[nt] = mW3[v * 64 + nt * 16 + ml];
        }
        float b3v = mb3[v];

        __syncthreads();   // W1B/W2B fully read before Hl (aliased) written

#pragma unroll
        for (int mt = 0; mt < 2; ++mt) {
            int lt = wid * 32 + mt * 16 + ml;
            bf16x8 a1 = *(bf16x8*)(Xl + lt * 40 + kb * 8);
            f32x4 c1[8] = {};
#pragma unroll
            for (int nt = 0; nt < 8; ++nt)
                c1[nt] = __builtin_amdgcn_mfma_f32_16x16x32_bf16(a1, w1f[nt], c1[nt], 0, 0, 0);
#pragma unroll
            for (int nt = 0; nt < 8; ++nt) {
#pragma unroll
                for (int r = 0; r < 4; ++r) {
                    int m = kb * 4 + r;
                    int h = nt * 16 + ml;
                    int bo = (m * 256 + h * 2) ^ ((m & 7) << 4);
                    *(short*)((char*)Hw + bo) = f2bf(fmaxf(c1[nt][r], 0.f));
                }
            }
            f32x4 c2[4] = {};
#pragma unroll
            for (int s = 0; s < 4; ++s) {
                int c0 = s * 32 + kb * 8;
                int bo = (ml * 256 + c0 * 2) ^ ((ml & 7) << 4);
                bf16x8 a2 = *(bf16x8*)((char*)Hw + bo);
#pragma unroll
                for (int nt = 0; nt < 4; ++nt)
                    c2[nt] = __builtin_amdgcn_mfma_f32_16x16x32_bf16(a2, w2f[s * 4 + nt], c2[nt], 0, 0, 0);
            }
            float sacc[4] = {0.f, 0.f, 0.f, 0.f};
#pragma unroll
            for (int nt = 0; nt < 4; ++nt) {
#pragma unroll
                for (int r = 0; r < 4; ++r)
                    sacc[r] += fmaxf(c2[nt][r] + b2r[nt], 0.f) * w3r[nt];
            }
#pragma unroll
            for (int o = 1; o < 16; o <<= 1) {
#pragma unroll
                for (int r = 0; r < 4; ++r)
                    sacc[r] += __shfl_xor(sacc[r], o);
            }
            if (ml == 0) {
                int tokb = chunk * 128 + wid * 32 + mt * 16 + kb * 4;
#pragma unroll
                for (int r = 0; r < 4; ++r)
                    out_pred[(tokb + r) * NV + v] = sacc[r] + b3v;
            }
        }
    } else {
        // ---------------- ind ----------------
        int p = bx - 768;
        int i = p / NV, j = p % NV;
        float w0[IH], w1[IH], bb[IH], w2[IH];
        const float4* A4 = (const float4*)(iW1 + p * 2 * IH);
        const float4* B4 = (const float4*)(ib1 + p * IH);
        const float4* C4 = (const float4*)(iW2 + p * IH);
#pragma unroll
        for (int q = 0; q < 8; ++q) {
            float4 u = A4[q];
            w0[q * 4 + 0] = u.x; w0[q * 4 + 1] = u.y; w0[q * 4 + 2] = u.z; w0[q * 4 + 3] = u.w;
            float4 v4 = A4[8 + q];
            w1[q * 4 + 0] = v4.x; w1[q * 4 + 1] = v4.y; w1[q * 4 + 2] = v4.z; w1[q * 4 + 3] = v4.w;
            float4 b4 = B4[q];
            bb[q * 4 + 0] = b4.x; bb[q * 4 + 1] = b4.y; bb[q * 4 + 2] = b4.z; bb[q * 4 + 3] = b4.w;
            float4 c4 = C4[q];
            w2[q * 4 + 0] = c4.x; w2[q * 4 + 1] = c4.y; w2[q * 4 + 2] = c4.z; w2[q * 4 + 3] = c4.w;
        }
        float b2v = ib2[p];
        const float* di_p = dataT + i * NTOK;
        const float* dj_p = dataT + j * NTOK;
        float acc = 0.f;
#pragma unroll 2
        for (int k = 0; k < NTOK / 256; ++k) {
            int n = k * 256 + t;
            float di = di_p[n];
            float dj = dj_p[n];
            float s = b2v;
#pragma unroll
            for (int h = 0; h < IH; ++h) {
                float a = fmaf(di, w0[h], fmaf(dj, w1[h], bb[h]));
                a = fmaxf(a, 0.f);
                s = fmaf(a, w2[h], s);
            }
            acc += 1.f / (1.f + expf(-s));
        }
        float* red = (float*)Xl;
        red[t] = acc;
        __syncthreads();
        for (int st = 128; st > 0; st >>= 1) {
            if (t < st) red[t] += red[t + st];
            __syncthreads();
        }
        if (t == 0) out_ind[p] = red[0] * (1.f / NTOK);
    }
}

extern "C" void kernel_launch(void* const* d_in, const int* in_sizes, int n_in,
                              void* d_out, int out_size, void* d_ws, size_t ws_size,
                              hipStream_t stream) {
    const float* data = (const float*)d_in[0];
    const float* sW1 = (const float*)d_in[1];
    const float* sb1 = (const float*)d_in[2];
    const float* sW2 = (const float*)d_in[3];
    const float* sb2 = (const float*)d_in[4];
    const float* sW3 = (const float*)d_in[5];
    const float* sb3 = (const float*)d_in[6];
    const float* mW1 = (const float*)d_in[7];
    const float* mb1 = (const float*)d_in[8];
    const float* mW2 = (const float*)d_in[9];
    const float* mb2 = (const float*)d_in[10];
    const float* mW3 = (const float*)d_in[11];
    const float* mb3 = (const float*)d_in[12];
    const float* iW1 = (const float*)d_in[13];
    const float* ib1 = (const float*)d_in[14];
    const float* iW2 = (const float*)d_in[15];
    const float* ib2 = (const float*)d_in[16];

    float* out = (float*)d_out;
    float* ws = (float*)d_ws;
    float* ws_cov = ws;
    float* ws_h1 = ws + 576;
    float* ws_h2 = ws + 832;
    float* ws_dataT = ws + 1024;
    float* ws_sW1T = ws + 99328;
    float* ws_sW2T = ws + 246784;
    float* ws_sW3T = ws + 279552;

    k_prep<<<dim3(446), dim3(256), 0, stream>>>(data, ws_dataT, sW1, sW2, sW3,
                                                ws_sW1T, ws_sW2T, ws_sW3T);
    k_cov<<<dim3(NP), dim3(256), 0, stream>>>(ws_dataT, ws_cov);
    k_adj1<<<dim3(SH1), dim3(256), 0, stream>>>(ws_cov, ws_sW1T, sb1, ws_h1);
    k_adj2<<<dim3(SH2), dim3(256), 0, stream>>>(ws_h1, ws_sW2T, sb2, ws_h2);
    k_adj3<<<dim3(NP), dim3(256), 0, stream>>>(ws_h2, ws_sW3T, sb3, out);
    k_predind<<<dim3(768 + NP), dim3(256), 0, stream>>>(
        data, mW1, mb1, mW2, mb2, mW3, mb3, out, out + NP,
        ws_dataT, iW1, ib1, iW2, ib2, out + NP + NTOK * NV);
}